// Round 10
// baseline (3156.351 us; speedup 1.0000x reference)
//
#include <hip/hip_runtime.h>

// LaplaceMeshLoss: COO Laplacian SpMV + per-row norm + weighted scalar reduce.
//
// R15 == R14 resubmitted (round 9 was an infra failure: container died twice;
// no counters). Theory unchanged:
//   Established: bucket gather pinned at ~312us invariant to bytes/ILP/L2
//   residency -> per-CU miss-concurrency limit on divergent VMEM ROUND-TRIPS.
//   Fix: col-bucketed products with LDS-window lookups + RETURNLESS global
//   f32 atomics into acc4[V] (fire-and-forget: no dependent load -> latency x
//   concurrency bound doesn't apply; new limit = L2 atomic-RMW throughput).
//     1) hist/scan/scatter by COLUMN bucket -> entries_c
//     2) product_atomic (per col-bucket): 2048-vert window coalesced -> LDS
//        (24KB); per entry: LDS lookup, 4 returnless atomics into acc4[row].
//     3) finalize: stream acc4 + verts + coefs coalesced, bnd-compare weights.
//   Removes: 312us bucket kernel, verts4 pack, 32KB accum LDS.
//   Non-determinism: float atomic order only (tolerance passed 0.03125).
//   Fallbacks: R8 row-sort+gather path (~120MB), then R1 path.
//
// ws layout (R14/R15 path):
//   [0,8)        double partial
//   [8,24)       int nvpm[4]
//   [24,40)      int bnd[4]
//   [64,8260)    uint base_c[2049]
//   [16384,...)  uint total_c[2048]
//   [262144,+4MB)   ushort hist_c[BMAX*NB]
//   [+112MB)        uint2  entries_c[NNZ]
//   [+32MB)         float4 acc4[V]

#define NB 1024           // chunk-blocks in hist/scatter; hist row width
#define BMAX 2048
#define BROWS 2048        // rows (and cols) per bucket -> 11 bits

__global__ void hist_kernel(const int* __restrict__ keys, int nnz, int cpb,
                            int B, unsigned short* __restrict__ hist) {
    __shared__ unsigned h[BMAX];
    for (int b = threadIdx.x; b < B; b += blockDim.x) h[b] = 0;
    __syncthreads();
    int k = blockIdx.x;
    int i0 = k * cpb;
    int i1 = min(i0 + cpb, nnz);
    for (int i = i0 + 4 * (int)threadIdx.x; i < i1; i += 4 * blockDim.x) {
        if (i + 3 < i1) {
            int4 r4 = *(const int4*)(keys + i);
            atomicAdd(&h[r4.x >> 11], 1u);
            atomicAdd(&h[r4.y >> 11], 1u);
            atomicAdd(&h[r4.z >> 11], 1u);
            atomicAdd(&h[r4.w >> 11], 1u);
        } else {
            for (int j = i; j < i1; ++j) atomicAdd(&h[keys[j] >> 11], 1u);
        }
    }
    __syncthreads();
    for (int b = threadIdx.x; b < B; b += blockDim.x)
        hist[(size_t)b * NB + k] = (unsigned short)h[b];
}

// One block per bucket: exclusive scan of hist[b][0..NB) in place (ushort).
__global__ void scan_blocks_kernel(unsigned short* __restrict__ hist,
                                   unsigned* __restrict__ total) {
    int b = blockIdx.x;
    int t = threadIdx.x;            // 256 threads
    int lane = t & 63, wave = t >> 6;
    unsigned short* hp = hist + (size_t)b * NB;
    ushort4 hv = ((const ushort4*)hp)[t];
    unsigned a0 = hv.x, a1 = hv.y, a2 = hv.z, a3 = hv.w;
    unsigned sum = a0 + a1 + a2 + a3;
    unsigned x = sum;
    for (int off = 1; off < 64; off <<= 1) {
        unsigned y = __shfl_up(x, off);
        if (lane >= off) x += y;
    }
    __shared__ unsigned wsum[4];
    if (lane == 63) wsum[wave] = x;
    __syncthreads();
    unsigned woff = 0;
    for (int w = 0; w < wave; ++w) woff += wsum[w];
    unsigned excl = woff + x - sum;
    ushort4 ov;
    ov.x = (unsigned short)excl;
    ov.y = (unsigned short)(excl + a0);
    ov.z = (unsigned short)(excl + a0 + a1);
    ov.w = (unsigned short)(excl + a0 + a1 + a2);
    ((ushort4*)hp)[t] = ov;
    if (t == 255) total[b] = woff + x;
}

__global__ void scan_buckets_kernel(const unsigned* __restrict__ total,
                                    unsigned* __restrict__ base, int B,
                                    const int* __restrict__ mesh_idx, int v,
                                    int* __restrict__ nvpm,
                                    int* __restrict__ bnd) {
    int t = threadIdx.x;            // 1024 threads, 2 elems each
    if (t < 4) {
        auto lb = [&](int tgt) {
            int lo = 0, hi = v;
            while (lo < hi) {
                int mid = (lo + hi) >> 1;
                if (mesh_idx[mid] < tgt) lo = mid + 1; else hi = mid;
            }
            return lo;
        };
        int hi_b = lb(t + 1);
        nvpm[t] = hi_b - lb(t);
        bnd[t]  = hi_b;
    }
    __shared__ unsigned buf0[1024], buf1[1024];
    unsigned x0 = (2 * t < B) ? total[2 * t] : 0u;
    unsigned x1 = (2 * t + 1 < B) ? total[2 * t + 1] : 0u;
    unsigned pair = x0 + x1;
    buf0[t] = pair;
    __syncthreads();
    unsigned* src = buf0;
    unsigned* dst = buf1;
    unsigned vv = pair;
    for (int off = 1; off < 1024; off <<= 1) {
        vv = src[t];
        if (t >= off) vv += src[t - off];
        dst[t] = vv;
        __syncthreads();
        unsigned* tmp = src; src = dst; dst = tmp;
    }
    unsigned excl = vv - pair;
    base[2 * t] = excl;
    base[2 * t + 1] = excl + x0;
    if (t == 1023) base[2048] = vv;
}

// COLMODE: key = cols, payload (colLow<<21)|row (needs V <= 2^21).
// !COLMODE: key = rows, payload (rowLow<<21)|col  (R8 fallback path).
template <bool COLMODE>
__global__ void scatter_kernel(const int* __restrict__ rows,
                               const int* __restrict__ cols,
                               const float* __restrict__ vals,
                               const unsigned short* __restrict__ hist,
                               const unsigned* __restrict__ base,
                               uint2* __restrict__ dst,
                               int nnz, int cpb, int B) {
    __shared__ unsigned cur[BMAX];
    int k = blockIdx.x;
    for (int b = threadIdx.x; b < B; b += blockDim.x)
        cur[b] = base[b] + hist[(size_t)b * NB + k];
    __syncthreads();
    int i0 = k * cpb;
    int i1 = min(i0 + cpb, nnz);
    for (int i = i0 + 4 * (int)threadIdx.x; i < i1; i += 4 * blockDim.x) {
        if (i + 3 < i1) {
            int4   r4 = *(const int4*)(rows + i);
            int4   c4 = *(const int4*)(cols + i);
            float4 v4 = *(const float4*)(vals + i);
            int k0 = COLMODE ? c4.x : r4.x;
            int k1 = COLMODE ? c4.y : r4.y;
            int k2 = COLMODE ? c4.z : r4.z;
            int k3 = COLMODE ? c4.w : r4.w;
            int o0 = COLMODE ? r4.x : c4.x;
            int o1 = COLMODE ? r4.y : c4.y;
            int o2 = COLMODE ? r4.z : c4.z;
            int o3 = COLMODE ? r4.w : c4.w;
            unsigned p0 = atomicAdd(&cur[k0 >> 11], 1u);
            unsigned p1 = atomicAdd(&cur[k1 >> 11], 1u);
            unsigned p2 = atomicAdd(&cur[k2 >> 11], 1u);
            unsigned p3 = atomicAdd(&cur[k3 >> 11], 1u);
            uint2 e0, e1, e2, e3;
            e0.x = ((unsigned)(k0 & (BROWS - 1)) << 21) | (unsigned)o0;
            e0.y = __float_as_uint(v4.x);
            e1.x = ((unsigned)(k1 & (BROWS - 1)) << 21) | (unsigned)o1;
            e1.y = __float_as_uint(v4.y);
            e2.x = ((unsigned)(k2 & (BROWS - 1)) << 21) | (unsigned)o2;
            e2.y = __float_as_uint(v4.z);
            e3.x = ((unsigned)(k3 & (BROWS - 1)) << 21) | (unsigned)o3;
            e3.y = __float_as_uint(v4.w);
            dst[p0] = e0;
            dst[p1] = e1;
            dst[p2] = e2;
            dst[p3] = e3;
        } else {
            for (int j = i; j < i1; ++j) {
                int kk = COLMODE ? cols[j] : rows[j];
                int oo = COLMODE ? rows[j] : cols[j];
                unsigned p = atomicAdd(&cur[kk >> 11], 1u);
                uint2 e;
                e.x = ((unsigned)(kk & (BROWS - 1)) << 21) | (unsigned)oo;
                e.y = __float_as_uint(vals[j]);
                dst[p] = e;
            }
        }
    }
}

// One block per col-bucket: verts window -> LDS (coalesced 24KB); per entry
// compute products from LDS and fire-and-forget global-atomic into acc4[row].
__global__ void __launch_bounds__(512)
product_atomic_kernel(const uint2* __restrict__ entries_c,
                      const unsigned* __restrict__ base_c,
                      const float* __restrict__ verts, int V,
                      float4* __restrict__ acc4) {
    __shared__ float wbuf[3 * BROWS];     // 24KB vertex window
    int bc = blockIdx.x;
    int c0 = bc << 11;
    int nfl = 3 * min(BROWS, V - c0);
    for (int j = threadIdx.x; j < nfl; j += blockDim.x)
        wbuf[j] = verts[3 * c0 + j];
    __syncthreads();
    unsigned s0 = base_c[bc], s1 = base_c[bc + 1];
    for (unsigned i = s0 + threadIdx.x; i < s1; i += blockDim.x) {
        uint2 e = entries_c[i];            // coalesced 8B stream
        unsigned colLow = e.x >> 21;
        unsigned row    = e.x & 0x1FFFFFu;
        float v = __uint_as_float(e.y);
        float x = wbuf[3 * colLow + 0];
        float y = wbuf[3 * colLow + 1];
        float z = wbuf[3 * colLow + 2];
        float* p = (float*)(acc4 + row);
        atomicAdd(p + 0, v * x);           // returnless -> no wave stall
        atomicAdd(p + 1, v * y);
        atomicAdd(p + 2, v * z);
        atomicAdd(p + 3, v);
    }
}

// Streaming finalize: acc4 + verts + coefs coalesced; bnd-compare weights.
__global__ void finalize_kernel(const float4* __restrict__ acc4,
                                const float* __restrict__ verts,
                                const float* __restrict__ coefs,
                                const int* __restrict__ bnd,
                                const int* __restrict__ nvpm,
                                double* __restrict__ partial, int v) {
    float inv0 = 1.0f / (float)nvpm[0];
    float inv1 = 1.0f / (float)nvpm[1];
    float inv2 = 1.0f / (float)nvpm[2];
    float inv3 = 1.0f / (float)nvpm[3];
    int bd0 = bnd[0], bd1 = bnd[1], bd2 = bnd[2];
    double acc_sum = 0.0;
    for (int i = blockIdx.x * blockDim.x + threadIdx.x; i < v;
         i += gridDim.x * blockDim.x) {
        float4 a = acc4[i];
        float rs = a.w;
        float nw = (rs > 0.0f) ? (1.0f / rs) : rs;
        float r0 = a.x * nw - verts[3 * i + 0];
        float r1 = a.y * nw - verts[3 * i + 1];
        float r2 = a.z * nw - verts[3 * i + 2];
        float loss = sqrtf(r0 * r0 + r1 * r1 + r2 * r2);
        float w = (i < bd0) ? inv0 : (i < bd1) ? inv1 : (i < bd2) ? inv2
                                                                  : inv3;
        acc_sum += (double)(loss * w * coefs[i]);
    }
    __shared__ double sred[256];
    sred[threadIdx.x] = acc_sum;
    __syncthreads();
    for (int s = blockDim.x / 2; s > 0; s >>= 1) {
        if (threadIdx.x < s) sred[threadIdx.x] += sred[threadIdx.x + s];
        __syncthreads();
    }
    if (threadIdx.x == 0) atomicAdd(partial, sred[0]);
}

// R8 fallback bucket kernel (raw verts gathers + LDS atomics).
__global__ void bucket_kernel(const uint2* __restrict__ entries,
                              const unsigned* __restrict__ base,
                              const float* __restrict__ verts,
                              const float* __restrict__ coefs,
                              const int* __restrict__ bnd,
                              const int* __restrict__ nvpm,
                              double* __restrict__ partial, int V) {
    __shared__ float ax[BROWS], ay[BROWS], az[BROWS], aw[BROWS];
    int b = blockIdx.x;
    for (int j = threadIdx.x; j < BROWS; j += blockDim.x) {
        ax[j] = 0.f; ay[j] = 0.f; az[j] = 0.f; aw[j] = 0.f;
    }
    __syncthreads();
    unsigned s0 = base[b], s1 = base[b + 1];
    for (unsigned i = s0 + threadIdx.x; i < s1; i += blockDim.x) {
        uint2 e = entries[i];
        unsigned lr = e.x >> 21;
        unsigned c  = e.x & 0x1FFFFFu;
        float v = __uint_as_float(e.y);
        float x = verts[3 * c + 0];
        float y = verts[3 * c + 1];
        float z = verts[3 * c + 2];
        atomicAdd(&ax[lr], v * x);
        atomicAdd(&ay[lr], v * y);
        atomicAdd(&az[lr], v * z);
        atomicAdd(&aw[lr], v);
    }
    __syncthreads();

    float inv0 = 1.0f / (float)nvpm[0];
    float inv1 = 1.0f / (float)nvpm[1];
    float inv2 = 1.0f / (float)nvpm[2];
    float inv3 = 1.0f / (float)nvpm[3];
    int bd0 = bnd[0], bd1 = bnd[1], bd2 = bnd[2];

    double acc = 0.0;
    int r0 = b << 11;
    for (int j = threadIdx.x; j < BROWS; j += blockDim.x) {
        int r = r0 + j;
        if (r < V) {
            float rs = aw[j];
            float nw = (rs > 0.0f) ? (1.0f / rs) : rs;
            float d0 = ax[j] * nw - verts[3 * r + 0];
            float d1 = ay[j] * nw - verts[3 * r + 1];
            float d2 = az[j] * nw - verts[3 * r + 2];
            float loss = sqrtf(d0 * d0 + d1 * d1 + d2 * d2);
            float w = (r < bd0) ? inv0 : (r < bd1) ? inv1 : (r < bd2) ? inv2
                                                                      : inv3;
            acc += (double)(loss * w * coefs[r]);
        }
    }

    __shared__ double sred[512];
    sred[threadIdx.x] = acc;
    __syncthreads();
    for (int s = blockDim.x / 2; s > 0; s >>= 1) {
        if (threadIdx.x < s) sred[threadIdx.x] += sred[threadIdx.x + s];
        __syncthreads();
    }
    if (threadIdx.x == 0) atomicAdd(partial, sred[0]);
}

__global__ void write_out_kernel(const double* __restrict__ partial,
                                 float* __restrict__ out) {
    if (threadIdx.x == 0 && blockIdx.x == 0)
        out[0] = (float)(partial[0] * 0.25);  // / N_MESHES
}

// ---- Fallback path (R1): global-atomic scatter, needs only 64 + 16V ws ----

__global__ void fb_mesh_counts_kernel(const int* __restrict__ mesh_idx, int v,
                                      int* __restrict__ nvpm) {
    int m = threadIdx.x;
    if (m >= 4) return;
    auto lb = [&](int t) {
        int lo = 0, hi = v;
        while (lo < hi) {
            int mid = (lo + hi) >> 1;
            if (mesh_idx[mid] < t) lo = mid + 1; else hi = mid;
        }
        return lo;
    };
    nvpm[m] = lb(m + 1) - lb(m);
}

__global__ void fb_scatter_kernel(const float* __restrict__ verts,
                                  const float* __restrict__ vals,
                                  const int* __restrict__ rows,
                                  const int* __restrict__ cols,
                                  float* __restrict__ acc, int nnz) {
    int i = blockIdx.x * blockDim.x + threadIdx.x;
    if (i >= nnz) return;
    int r = rows[i];
    int c = cols[i];
    float v = vals[i];
    float* p = acc + 4ll * r;
    atomicAdd(p + 0, v * verts[3 * c + 0]);
    atomicAdd(p + 1, v * verts[3 * c + 1]);
    atomicAdd(p + 2, v * verts[3 * c + 2]);
    atomicAdd(p + 3, v);
}

__global__ void fb_finalize_kernel(const float* __restrict__ verts,
                                   const float* __restrict__ coefs,
                                   const int* __restrict__ mesh_idx,
                                   const float4* __restrict__ acc,
                                   const int* __restrict__ nvpm,
                                   double* __restrict__ partial, int v) {
    float inv0 = 1.0f / (float)nvpm[0];
    float inv1 = 1.0f / (float)nvpm[1];
    float inv2 = 1.0f / (float)nvpm[2];
    float inv3 = 1.0f / (float)nvpm[3];
    double acc_sum = 0.0;
    for (int i = blockIdx.x * blockDim.x + threadIdx.x; i < v;
         i += gridDim.x * blockDim.x) {
        float4 a = acc[i];
        float rs = a.w;
        float nw = (rs > 0.0f) ? (1.0f / rs) : rs;
        float r0 = a.x * nw - verts[3 * i + 0];
        float r1 = a.y * nw - verts[3 * i + 1];
        float r2 = a.z * nw - verts[3 * i + 2];
        float loss = sqrtf(r0 * r0 + r1 * r1 + r2 * r2);
        int m = mesh_idx[i];
        float w = (m == 0) ? inv0 : (m == 1) ? inv1 : (m == 2) ? inv2 : inv3;
        acc_sum += (double)(loss * w * coefs[i]);
    }
    __shared__ double sred[256];
    sred[threadIdx.x] = acc_sum;
    __syncthreads();
    for (int s = blockDim.x / 2; s > 0; s >>= 1) {
        if (threadIdx.x < s) sred[threadIdx.x] += sred[threadIdx.x + s];
        __syncthreads();
    }
    if (threadIdx.x == 0) atomicAdd(partial, sred[0]);
}

extern "C" void kernel_launch(void* const* d_in, const int* in_sizes, int n_in,
                              void* d_out, int out_size, void* d_ws, size_t ws_size,
                              hipStream_t stream) {
    const float* verts    = (const float*)d_in[0];
    const float* lap_vals = (const float*)d_in[1];
    const int*   lap_rows = (const int*)d_in[2];
    const int*   lap_cols = (const int*)d_in[3];
    const int*   mesh_idx = (const int*)d_in[4];
    const float* coefs    = (const float*)d_in[5];
    float* out = (float*)d_out;

    const int V   = in_sizes[0] / 3;
    const int NNZ = in_sizes[1];
    const int B   = (V + BROWS - 1) / BROWS;   // 977 for V = 2M
    int cpb = (NNZ + NB - 1) / NB;
    cpb = (cpb + 3) & ~3;

    char* ws = (char*)d_ws;
    const size_t off_histc   = 262144;
    const size_t off_entries = off_histc + (size_t)BMAX * NB * 2;       // +4MB
    const size_t off_acc4    = (off_entries + (size_t)NNZ * 8 + 255)
                               & ~(size_t)255;
    double*         partial  = (double*)(ws + 0);
    int*            nvpm     = (int*)(ws + 8);
    int*            bnd      = (int*)(ws + 24);
    unsigned*       base_c   = (unsigned*)(ws + 64);
    unsigned*       total_c  = (unsigned*)(ws + 16384);
    unsigned short* hist_c   = (unsigned short*)(ws + off_histc);
    uint2*          entries  = (uint2*)(ws + off_entries);
    float4*         acc4     = (float4*)(ws + off_acc4);

    size_t r14_need  = off_acc4 + (size_t)16 * V + 64;           // ~149 MB
    size_t sort_need = off_entries + (size_t)NNZ * 8 + 64;       // ~120 MB

    (void)hipMemsetAsync(d_ws, 0, 64, stream);

    bool ok_pack = (V <= (1 << 21)) && (B <= NB) && (B <= BMAX);
    if (ws_size >= r14_need && ok_pack) {
        (void)hipMemsetAsync(ws + off_acc4, 0, (size_t)16 * V, stream);
        hist_kernel<<<NB, 256, 0, stream>>>(lap_cols, NNZ, cpb, B, hist_c);
        scan_blocks_kernel<<<B, 256, 0, stream>>>(hist_c, total_c);
        scan_buckets_kernel<<<1, 1024, 0, stream>>>(total_c, base_c, B,
                                                    mesh_idx, V, nvpm, bnd);
        scatter_kernel<true><<<NB, 256, 0, stream>>>(
            lap_rows, lap_cols, lap_vals, hist_c, base_c, entries, NNZ, cpb, B);
        product_atomic_kernel<<<B, 512, 0, stream>>>(entries, base_c,
                                                     verts, V, acc4);
        finalize_kernel<<<2048, 256, 0, stream>>>(acc4, verts, coefs, bnd,
                                                  nvpm, partial, V);
    } else if (ws_size >= sort_need && ok_pack) {
        // R8 fallback: row-sort + gather bucket kernel
        hist_kernel<<<NB, 256, 0, stream>>>(lap_rows, NNZ, cpb, B, hist_c);
        scan_blocks_kernel<<<B, 256, 0, stream>>>(hist_c, total_c);
        scan_buckets_kernel<<<1, 1024, 0, stream>>>(total_c, base_c, B,
                                                    mesh_idx, V, nvpm, bnd);
        scatter_kernel<false><<<NB, 256, 0, stream>>>(
            lap_rows, lap_cols, lap_vals, hist_c, base_c, entries, NNZ, cpb, B);
        bucket_kernel<<<B, 512, 0, stream>>>(entries, base_c, verts, coefs,
                                             bnd, nvpm, partial, V);
    } else {
        float* acc = (float*)(ws + 64);
        (void)hipMemsetAsync(ws + 64, 0, (size_t)16 * V, stream);
        fb_mesh_counts_kernel<<<1, 64, 0, stream>>>(mesh_idx, V, nvpm);
        fb_scatter_kernel<<<(NNZ + 255) / 256, 256, 0, stream>>>(
            verts, lap_vals, lap_rows, lap_cols, acc, NNZ);
        fb_finalize_kernel<<<2048, 256, 0, stream>>>(
            verts, coefs, mesh_idx, (const float4*)acc, nvpm, partial, V);
    }

    write_out_kernel<<<1, 64, 0, stream>>>(partial, out);
}

// Round 11
// 682.995 us; speedup vs baseline: 4.6213x; 4.6213x over previous
//
#include <hip/hip_runtime.h>

// LaplaceMeshLoss: COO Laplacian SpMV + per-row norm + weighted scalar reduce.
//
// R16: revert to the best harness-verified configuration (R8 middle path,
// 680.3us measured in round 8) after R14/R15 falsified the global-atomic
// design (product_atomic 2748us: 56M scattered device-scope f32 RMWs ~20 G/s,
// acc4 lines ping-pong across 8 non-coherent XCD L2s; WRITE_SIZE 1.75GB).
//
// Wall map (measured, rounds 1-10):
//   - bucket accumulate: ~310us, INVARIANT to fetched bytes (848/730/201MB),
//     gather ILP (1/2/4-wide), request count (14M float4 == 42M scalar), and
//     L2 residency (enforced phasing). Per-entry pipeline cost (DS-atomic
//     RMW occupancy vs dependent VMEM chain - not separable with PMC set).
//   - global atomic RMW: ~20 G/s (R14) -> unusable for 56M ops.
//   - streaming: 3.3 TB/s sustained (R12).
//   - staging (hist+scans+scatter): ~370us.
// Structure: hist/scan/scatter by row-bucket -> bucket_kernel (raw verts
// gather + 4 LDS atomics/entry + fused bnd-compare finalize) -> write_out.
// Fallback: R1 global-atomic path for small ws.
//
// ws layout:
//   [0,8)        double partial
//   [8,24)       int nvpm[4]
//   [24,40)      int bnd[4]
//   [64,8260)    uint base[2049]
//   [16384,...)  uint total[2048]
//   [262144,+4MB)   ushort hist[BMAX*NB]
//   [+112MB)        uint2 entries[NNZ]

#define NB 1024           // chunk-blocks in hist/scatter; hist row width
#define BMAX 2048
#define BROWS 2048        // rows per bucket -> 11 bits

__global__ void hist_kernel(const int* __restrict__ keys, int nnz, int cpb,
                            int B, unsigned short* __restrict__ hist) {
    __shared__ unsigned h[BMAX];
    for (int b = threadIdx.x; b < B; b += blockDim.x) h[b] = 0;
    __syncthreads();
    int k = blockIdx.x;
    int i0 = k * cpb;
    int i1 = min(i0 + cpb, nnz);
    for (int i = i0 + 4 * (int)threadIdx.x; i < i1; i += 4 * blockDim.x) {
        if (i + 3 < i1) {
            int4 r4 = *(const int4*)(keys + i);
            atomicAdd(&h[r4.x >> 11], 1u);
            atomicAdd(&h[r4.y >> 11], 1u);
            atomicAdd(&h[r4.z >> 11], 1u);
            atomicAdd(&h[r4.w >> 11], 1u);
        } else {
            for (int j = i; j < i1; ++j) atomicAdd(&h[keys[j] >> 11], 1u);
        }
    }
    __syncthreads();
    for (int b = threadIdx.x; b < B; b += blockDim.x)
        hist[(size_t)b * NB + k] = (unsigned short)h[b];
}

// One block per bucket: exclusive scan of hist[b][0..NB) in place (ushort).
__global__ void scan_blocks_kernel(unsigned short* __restrict__ hist,
                                   unsigned* __restrict__ total) {
    int b = blockIdx.x;
    int t = threadIdx.x;            // 256 threads
    int lane = t & 63, wave = t >> 6;
    unsigned short* hp = hist + (size_t)b * NB;
    ushort4 hv = ((const ushort4*)hp)[t];
    unsigned a0 = hv.x, a1 = hv.y, a2 = hv.z, a3 = hv.w;
    unsigned sum = a0 + a1 + a2 + a3;
    unsigned x = sum;
    for (int off = 1; off < 64; off <<= 1) {
        unsigned y = __shfl_up(x, off);
        if (lane >= off) x += y;
    }
    __shared__ unsigned wsum[4];
    if (lane == 63) wsum[wave] = x;
    __syncthreads();
    unsigned woff = 0;
    for (int w = 0; w < wave; ++w) woff += wsum[w];
    unsigned excl = woff + x - sum;
    ushort4 ov;
    ov.x = (unsigned short)excl;
    ov.y = (unsigned short)(excl + a0);
    ov.z = (unsigned short)(excl + a0 + a1);
    ov.w = (unsigned short)(excl + a0 + a1 + a2);
    ((ushort4*)hp)[t] = ov;
    if (t == 255) total[b] = woff + x;
}

__global__ void scan_buckets_kernel(const unsigned* __restrict__ total,
                                    unsigned* __restrict__ base, int B,
                                    const int* __restrict__ mesh_idx, int v,
                                    int* __restrict__ nvpm,
                                    int* __restrict__ bnd) {
    int t = threadIdx.x;            // 1024 threads, 2 elems each
    if (t < 4) {
        auto lb = [&](int tgt) {
            int lo = 0, hi = v;
            while (lo < hi) {
                int mid = (lo + hi) >> 1;
                if (mesh_idx[mid] < tgt) lo = mid + 1; else hi = mid;
            }
            return lo;
        };
        int hi_b = lb(t + 1);
        nvpm[t] = hi_b - lb(t);
        bnd[t]  = hi_b;
    }
    __shared__ unsigned buf0[1024], buf1[1024];
    unsigned x0 = (2 * t < B) ? total[2 * t] : 0u;
    unsigned x1 = (2 * t + 1 < B) ? total[2 * t + 1] : 0u;
    unsigned pair = x0 + x1;
    buf0[t] = pair;
    __syncthreads();
    unsigned* src = buf0;
    unsigned* dst = buf1;
    unsigned vv = pair;
    for (int off = 1; off < 1024; off <<= 1) {
        vv = src[t];
        if (t >= off) vv += src[t - off];
        dst[t] = vv;
        __syncthreads();
        unsigned* tmp = src; src = dst; dst = tmp;
    }
    unsigned excl = vv - pair;
    base[2 * t] = excl;
    base[2 * t + 1] = excl + x0;
    if (t == 1023) base[2048] = vv;
}

// key = rows, payload (rowLow<<21)|col  (needs V <= 2^21).
__global__ void scatter_kernel(const int* __restrict__ rows,
                               const int* __restrict__ cols,
                               const float* __restrict__ vals,
                               const unsigned short* __restrict__ hist,
                               const unsigned* __restrict__ base,
                               uint2* __restrict__ dst,
                               int nnz, int cpb, int B) {
    __shared__ unsigned cur[BMAX];
    int k = blockIdx.x;
    for (int b = threadIdx.x; b < B; b += blockDim.x)
        cur[b] = base[b] + hist[(size_t)b * NB + k];
    __syncthreads();
    int i0 = k * cpb;
    int i1 = min(i0 + cpb, nnz);
    for (int i = i0 + 4 * (int)threadIdx.x; i < i1; i += 4 * blockDim.x) {
        if (i + 3 < i1) {
            int4   r4 = *(const int4*)(rows + i);
            int4   c4 = *(const int4*)(cols + i);
            float4 v4 = *(const float4*)(vals + i);
            unsigned p0 = atomicAdd(&cur[r4.x >> 11], 1u);
            unsigned p1 = atomicAdd(&cur[r4.y >> 11], 1u);
            unsigned p2 = atomicAdd(&cur[r4.z >> 11], 1u);
            unsigned p3 = atomicAdd(&cur[r4.w >> 11], 1u);
            uint2 e0, e1, e2, e3;
            e0.x = ((unsigned)(r4.x & (BROWS - 1)) << 21) | (unsigned)c4.x;
            e0.y = __float_as_uint(v4.x);
            e1.x = ((unsigned)(r4.y & (BROWS - 1)) << 21) | (unsigned)c4.y;
            e1.y = __float_as_uint(v4.y);
            e2.x = ((unsigned)(r4.z & (BROWS - 1)) << 21) | (unsigned)c4.z;
            e2.y = __float_as_uint(v4.z);
            e3.x = ((unsigned)(r4.w & (BROWS - 1)) << 21) | (unsigned)c4.w;
            e3.y = __float_as_uint(v4.w);
            dst[p0] = e0;
            dst[p1] = e1;
            dst[p2] = e2;
            dst[p3] = e3;
        } else {
            for (int j = i; j < i1; ++j) {
                int r = rows[j];
                unsigned p = atomicAdd(&cur[r >> 11], 1u);
                uint2 e;
                e.x = ((unsigned)(r & (BROWS - 1)) << 21) | (unsigned)cols[j];
                e.y = __float_as_uint(vals[j]);
                dst[p] = e;
            }
        }
    }
}

// One block (512 thr) per row-bucket: raw verts gather + 4 LDS atomics/entry,
// fused bnd-compare finalize. (310us measured; invariant to gather width.)
__global__ void bucket_kernel(const uint2* __restrict__ entries,
                              const unsigned* __restrict__ base,
                              const float* __restrict__ verts,
                              const float* __restrict__ coefs,
                              const int* __restrict__ bnd,
                              const int* __restrict__ nvpm,
                              double* __restrict__ partial, int V) {
    __shared__ float ax[BROWS], ay[BROWS], az[BROWS], aw[BROWS];
    int b = blockIdx.x;
    for (int j = threadIdx.x; j < BROWS; j += blockDim.x) {
        ax[j] = 0.f; ay[j] = 0.f; az[j] = 0.f; aw[j] = 0.f;
    }
    __syncthreads();
    unsigned s0 = base[b], s1 = base[b + 1];
    for (unsigned i = s0 + threadIdx.x; i < s1; i += blockDim.x) {
        uint2 e = entries[i];
        unsigned lr = e.x >> 21;
        unsigned c  = e.x & 0x1FFFFFu;
        float v = __uint_as_float(e.y);
        float x = verts[3 * c + 0];
        float y = verts[3 * c + 1];
        float z = verts[3 * c + 2];
        atomicAdd(&ax[lr], v * x);
        atomicAdd(&ay[lr], v * y);
        atomicAdd(&az[lr], v * z);
        atomicAdd(&aw[lr], v);
    }
    __syncthreads();

    float inv0 = 1.0f / (float)nvpm[0];
    float inv1 = 1.0f / (float)nvpm[1];
    float inv2 = 1.0f / (float)nvpm[2];
    float inv3 = 1.0f / (float)nvpm[3];
    int bd0 = bnd[0], bd1 = bnd[1], bd2 = bnd[2];

    double acc = 0.0;
    int r0 = b << 11;
    for (int j = threadIdx.x; j < BROWS; j += blockDim.x) {
        int r = r0 + j;
        if (r < V) {
            float rs = aw[j];
            float nw = (rs > 0.0f) ? (1.0f / rs) : rs;
            float d0 = ax[j] * nw - verts[3 * r + 0];
            float d1 = ay[j] * nw - verts[3 * r + 1];
            float d2 = az[j] * nw - verts[3 * r + 2];
            float loss = sqrtf(d0 * d0 + d1 * d1 + d2 * d2);
            float w = (r < bd0) ? inv0 : (r < bd1) ? inv1 : (r < bd2) ? inv2
                                                                      : inv3;
            acc += (double)(loss * w * coefs[r]);
        }
    }

    __shared__ double sred[512];
    sred[threadIdx.x] = acc;
    __syncthreads();
    for (int s = blockDim.x / 2; s > 0; s >>= 1) {
        if (threadIdx.x < s) sred[threadIdx.x] += sred[threadIdx.x + s];
        __syncthreads();
    }
    if (threadIdx.x == 0) atomicAdd(partial, sred[0]);
}

__global__ void write_out_kernel(const double* __restrict__ partial,
                                 float* __restrict__ out) {
    if (threadIdx.x == 0 && blockIdx.x == 0)
        out[0] = (float)(partial[0] * 0.25);  // / N_MESHES
}

// ---- Fallback path (R1): global-atomic scatter, needs only 64 + 16V ws ----

__global__ void fb_mesh_counts_kernel(const int* __restrict__ mesh_idx, int v,
                                      int* __restrict__ nvpm) {
    int m = threadIdx.x;
    if (m >= 4) return;
    auto lb = [&](int t) {
        int lo = 0, hi = v;
        while (lo < hi) {
            int mid = (lo + hi) >> 1;
            if (mesh_idx[mid] < t) lo = mid + 1; else hi = mid;
        }
        return lo;
    };
    nvpm[m] = lb(m + 1) - lb(m);
}

__global__ void fb_scatter_kernel(const float* __restrict__ verts,
                                  const float* __restrict__ vals,
                                  const int* __restrict__ rows,
                                  const int* __restrict__ cols,
                                  float* __restrict__ acc, int nnz) {
    int i = blockIdx.x * blockDim.x + threadIdx.x;
    if (i >= nnz) return;
    int r = rows[i];
    int c = cols[i];
    float v = vals[i];
    float* p = acc + 4ll * r;
    atomicAdd(p + 0, v * verts[3 * c + 0]);
    atomicAdd(p + 1, v * verts[3 * c + 1]);
    atomicAdd(p + 2, v * verts[3 * c + 2]);
    atomicAdd(p + 3, v);
}

__global__ void fb_finalize_kernel(const float* __restrict__ verts,
                                   const float* __restrict__ coefs,
                                   const int* __restrict__ mesh_idx,
                                   const float4* __restrict__ acc,
                                   const int* __restrict__ nvpm,
                                   double* __restrict__ partial, int v) {
    float inv0 = 1.0f / (float)nvpm[0];
    float inv1 = 1.0f / (float)nvpm[1];
    float inv2 = 1.0f / (float)nvpm[2];
    float inv3 = 1.0f / (float)nvpm[3];
    double acc_sum = 0.0;
    for (int i = blockIdx.x * blockDim.x + threadIdx.x; i < v;
         i += gridDim.x * blockDim.x) {
        float4 a = acc[i];
        float rs = a.w;
        float nw = (rs > 0.0f) ? (1.0f / rs) : rs;
        float r0 = a.x * nw - verts[3 * i + 0];
        float r1 = a.y * nw - verts[3 * i + 1];
        float r2 = a.z * nw - verts[3 * i + 2];
        float loss = sqrtf(r0 * r0 + r1 * r1 + r2 * r2);
        int m = mesh_idx[i];
        float w = (m == 0) ? inv0 : (m == 1) ? inv1 : (m == 2) ? inv2 : inv3;
        acc_sum += (double)(loss * w * coefs[i]);
    }
    __shared__ double sred[256];
    sred[threadIdx.x] = acc_sum;
    __syncthreads();
    for (int s = blockDim.x / 2; s > 0; s >>= 1) {
        if (threadIdx.x < s) sred[threadIdx.x] += sred[threadIdx.x + s];
        __syncthreads();
    }
    if (threadIdx.x == 0) atomicAdd(partial, sred[0]);
}

extern "C" void kernel_launch(void* const* d_in, const int* in_sizes, int n_in,
                              void* d_out, int out_size, void* d_ws, size_t ws_size,
                              hipStream_t stream) {
    const float* verts    = (const float*)d_in[0];
    const float* lap_vals = (const float*)d_in[1];
    const int*   lap_rows = (const int*)d_in[2];
    const int*   lap_cols = (const int*)d_in[3];
    const int*   mesh_idx = (const int*)d_in[4];
    const float* coefs    = (const float*)d_in[5];
    float* out = (float*)d_out;

    const int V   = in_sizes[0] / 3;
    const int NNZ = in_sizes[1];
    const int B   = (V + BROWS - 1) / BROWS;   // 977 for V = 2M
    int cpb = (NNZ + NB - 1) / NB;
    cpb = (cpb + 3) & ~3;

    char* ws = (char*)d_ws;
    const size_t off_hist    = 262144;
    const size_t off_entries = off_hist + (size_t)BMAX * NB * 2;        // +4MB
    double*         partial  = (double*)(ws + 0);
    int*            nvpm     = (int*)(ws + 8);
    int*            bnd      = (int*)(ws + 24);
    unsigned*       base     = (unsigned*)(ws + 64);
    unsigned*       total    = (unsigned*)(ws + 16384);
    unsigned short* hist     = (unsigned short*)(ws + off_hist);
    uint2*          entries  = (uint2*)(ws + off_entries);

    size_t sort_need = off_entries + (size_t)NNZ * 8 + 64;       // ~120 MB

    (void)hipMemsetAsync(d_ws, 0, 64, stream);

    bool ok_pack = (V <= (1 << 21)) && (B <= NB) && (B <= BMAX);
    if (ws_size >= sort_need && ok_pack) {
        hist_kernel<<<NB, 256, 0, stream>>>(lap_rows, NNZ, cpb, B, hist);
        scan_blocks_kernel<<<B, 256, 0, stream>>>(hist, total);
        scan_buckets_kernel<<<1, 1024, 0, stream>>>(total, base, B,
                                                    mesh_idx, V, nvpm, bnd);
        scatter_kernel<<<NB, 256, 0, stream>>>(
            lap_rows, lap_cols, lap_vals, hist, base, entries, NNZ, cpb, B);
        bucket_kernel<<<B, 512, 0, stream>>>(entries, base, verts, coefs,
                                             bnd, nvpm, partial, V);
    } else {
        float* acc = (float*)(ws + 64);
        (void)hipMemsetAsync(ws + 64, 0, (size_t)16 * V, stream);
        fb_mesh_counts_kernel<<<1, 64, 0, stream>>>(mesh_idx, V, nvpm);
        fb_scatter_kernel<<<(NNZ + 255) / 256, 256, 0, stream>>>(
            verts, lap_vals, lap_rows, lap_cols, acc, NNZ);
        fb_finalize_kernel<<<2048, 256, 0, stream>>>(
            verts, coefs, mesh_idx, (const float4*)acc, nvpm, partial, V);
    }

    write_out_kernel<<<1, 64, 0, stream>>>(partial, out);
}

// Round 12
// 655.986 us; speedup vs baseline: 4.8116x; 1.0412x over previous
//
#include <hip/hip_runtime.h>

// LaplaceMeshLoss: COO Laplacian SpMV + per-row norm + weighted scalar reduce.
//
// R17: staging attack — scatter store-run lengthening (NB 1024 -> 256).
//   R16 re-verified the 683us baseline (bucket 308us pinned; staging ~370us
//   vs ~120-170us streaming floor). Theory: scatter's 14M 8B stores into 977
//   bucket regions at NB=1024 give ~14-entry (112B) runs -> partial-line
//   writes / WC thrash (mirror of the gather wall). NB=256 with 512-thread
//   chunk blocks gives ~56-entry (448B) runs = full lines, 4x fewer open
//   regions per byte. hist work unchanged; scan_blocks becomes single-wave.
//   bucket_kernel byte-identical (verified 308us).
//   Prediction: scatter -40-50% if store-bound -> total ~550-590us; if flat,
//   staging is per-entry-pipeline-bound -> fuse passes next.
//
// ws layout:
//   [0,8)        double partial
//   [8,24)       int nvpm[4]
//   [24,40)      int bnd[4]
//   [64,8260)    uint base[2049]
//   [16384,...)  uint total[2048]
//   [262144,+1MB)   ushort hist[BMAX*NB]
//   [+112MB)        uint2 entries[NNZ]

#define NB 256            // chunk-blocks in hist/scatter; hist row width
#define BMAX 2048
#define BROWS 2048        // rows per bucket -> 11 bits

__global__ void hist_kernel(const int* __restrict__ keys, int nnz, int cpb,
                            int B, unsigned short* __restrict__ hist) {
    __shared__ unsigned h[BMAX];
    for (int b = threadIdx.x; b < B; b += blockDim.x) h[b] = 0;
    __syncthreads();
    int k = blockIdx.x;
    int i0 = k * cpb;
    int i1 = min(i0 + cpb, nnz);
    for (int i = i0 + 4 * (int)threadIdx.x; i < i1; i += 4 * blockDim.x) {
        if (i + 3 < i1) {
            int4 r4 = *(const int4*)(keys + i);
            atomicAdd(&h[r4.x >> 11], 1u);
            atomicAdd(&h[r4.y >> 11], 1u);
            atomicAdd(&h[r4.z >> 11], 1u);
            atomicAdd(&h[r4.w >> 11], 1u);
        } else {
            for (int j = i; j < i1; ++j) atomicAdd(&h[keys[j] >> 11], 1u);
        }
    }
    __syncthreads();
    for (int b = threadIdx.x; b < B; b += blockDim.x)
        hist[(size_t)b * NB + k] = (unsigned short)h[b];
}

// One block (1 wave) per bucket: exclusive scan of hist[b][0..NB) in place.
__global__ void scan_blocks_kernel(unsigned short* __restrict__ hist,
                                   unsigned* __restrict__ total) {
    int b = blockIdx.x;
    int t = threadIdx.x;            // 64 threads = 1 wave, 4 elems each
    unsigned short* hp = hist + (size_t)b * NB;
    ushort4 hv = ((const ushort4*)hp)[t];
    unsigned a0 = hv.x, a1 = hv.y, a2 = hv.z, a3 = hv.w;
    unsigned sum = a0 + a1 + a2 + a3;
    unsigned x = sum;
    for (int off = 1; off < 64; off <<= 1) {
        unsigned y = __shfl_up(x, off);
        if (t >= off) x += y;
    }
    unsigned excl = x - sum;
    ushort4 ov;
    ov.x = (unsigned short)excl;
    ov.y = (unsigned short)(excl + a0);
    ov.z = (unsigned short)(excl + a0 + a1);
    ov.w = (unsigned short)(excl + a0 + a1 + a2);
    ((ushort4*)hp)[t] = ov;
    if (t == 63) total[b] = x;
}

__global__ void scan_buckets_kernel(const unsigned* __restrict__ total,
                                    unsigned* __restrict__ base, int B,
                                    const int* __restrict__ mesh_idx, int v,
                                    int* __restrict__ nvpm,
                                    int* __restrict__ bnd) {
    int t = threadIdx.x;            // 1024 threads, 2 elems each
    if (t < 4) {
        auto lb = [&](int tgt) {
            int lo = 0, hi = v;
            while (lo < hi) {
                int mid = (lo + hi) >> 1;
                if (mesh_idx[mid] < tgt) lo = mid + 1; else hi = mid;
            }
            return lo;
        };
        int hi_b = lb(t + 1);
        nvpm[t] = hi_b - lb(t);
        bnd[t]  = hi_b;
    }
    __shared__ unsigned buf0[1024], buf1[1024];
    unsigned x0 = (2 * t < B) ? total[2 * t] : 0u;
    unsigned x1 = (2 * t + 1 < B) ? total[2 * t + 1] : 0u;
    unsigned pair = x0 + x1;
    buf0[t] = pair;
    __syncthreads();
    unsigned* src = buf0;
    unsigned* dst = buf1;
    unsigned vv = pair;
    for (int off = 1; off < 1024; off <<= 1) {
        vv = src[t];
        if (t >= off) vv += src[t - off];
        dst[t] = vv;
        __syncthreads();
        unsigned* tmp = src; src = dst; dst = tmp;
    }
    unsigned excl = vv - pair;
    base[2 * t] = excl;
    base[2 * t + 1] = excl + x0;
    if (t == 1023) base[2048] = vv;
}

// key = rows, payload (rowLow<<21)|col  (needs V <= 2^21).
__global__ void __launch_bounds__(512)
scatter_kernel(const int* __restrict__ rows,
               const int* __restrict__ cols,
               const float* __restrict__ vals,
               const unsigned short* __restrict__ hist,
               const unsigned* __restrict__ base,
               uint2* __restrict__ dst,
               int nnz, int cpb, int B) {
    __shared__ unsigned cur[BMAX];
    int k = blockIdx.x;
    for (int b = threadIdx.x; b < B; b += blockDim.x)
        cur[b] = base[b] + hist[(size_t)b * NB + k];
    __syncthreads();
    int i0 = k * cpb;
    int i1 = min(i0 + cpb, nnz);
    for (int i = i0 + 4 * (int)threadIdx.x; i < i1; i += 4 * blockDim.x) {
        if (i + 3 < i1) {
            int4   r4 = *(const int4*)(rows + i);
            int4   c4 = *(const int4*)(cols + i);
            float4 v4 = *(const float4*)(vals + i);
            unsigned p0 = atomicAdd(&cur[r4.x >> 11], 1u);
            unsigned p1 = atomicAdd(&cur[r4.y >> 11], 1u);
            unsigned p2 = atomicAdd(&cur[r4.z >> 11], 1u);
            unsigned p3 = atomicAdd(&cur[r4.w >> 11], 1u);
            uint2 e0, e1, e2, e3;
            e0.x = ((unsigned)(r4.x & (BROWS - 1)) << 21) | (unsigned)c4.x;
            e0.y = __float_as_uint(v4.x);
            e1.x = ((unsigned)(r4.y & (BROWS - 1)) << 21) | (unsigned)c4.y;
            e1.y = __float_as_uint(v4.y);
            e2.x = ((unsigned)(r4.z & (BROWS - 1)) << 21) | (unsigned)c4.z;
            e2.y = __float_as_uint(v4.z);
            e3.x = ((unsigned)(r4.w & (BROWS - 1)) << 21) | (unsigned)c4.w;
            e3.y = __float_as_uint(v4.w);
            dst[p0] = e0;
            dst[p1] = e1;
            dst[p2] = e2;
            dst[p3] = e3;
        } else {
            for (int j = i; j < i1; ++j) {
                int r = rows[j];
                unsigned p = atomicAdd(&cur[r >> 11], 1u);
                uint2 e;
                e.x = ((unsigned)(r & (BROWS - 1)) << 21) | (unsigned)cols[j];
                e.y = __float_as_uint(vals[j]);
                dst[p] = e;
            }
        }
    }
}

// One block (512 thr) per row-bucket: raw verts gather + 4 LDS atomics/entry,
// fused bnd-compare finalize. (308us measured; invariant to gather width.)
__global__ void bucket_kernel(const uint2* __restrict__ entries,
                              const unsigned* __restrict__ base,
                              const float* __restrict__ verts,
                              const float* __restrict__ coefs,
                              const int* __restrict__ bnd,
                              const int* __restrict__ nvpm,
                              double* __restrict__ partial, int V) {
    __shared__ float ax[BROWS], ay[BROWS], az[BROWS], aw[BROWS];
    int b = blockIdx.x;
    for (int j = threadIdx.x; j < BROWS; j += blockDim.x) {
        ax[j] = 0.f; ay[j] = 0.f; az[j] = 0.f; aw[j] = 0.f;
    }
    __syncthreads();
    unsigned s0 = base[b], s1 = base[b + 1];
    for (unsigned i = s0 + threadIdx.x; i < s1; i += blockDim.x) {
        uint2 e = entries[i];
        unsigned lr = e.x >> 21;
        unsigned c  = e.x & 0x1FFFFFu;
        float v = __uint_as_float(e.y);
        float x = verts[3 * c + 0];
        float y = verts[3 * c + 1];
        float z = verts[3 * c + 2];
        atomicAdd(&ax[lr], v * x);
        atomicAdd(&ay[lr], v * y);
        atomicAdd(&az[lr], v * z);
        atomicAdd(&aw[lr], v);
    }
    __syncthreads();

    float inv0 = 1.0f / (float)nvpm[0];
    float inv1 = 1.0f / (float)nvpm[1];
    float inv2 = 1.0f / (float)nvpm[2];
    float inv3 = 1.0f / (float)nvpm[3];
    int bd0 = bnd[0], bd1 = bnd[1], bd2 = bnd[2];

    double acc = 0.0;
    int r0 = b << 11;
    for (int j = threadIdx.x; j < BROWS; j += blockDim.x) {
        int r = r0 + j;
        if (r < V) {
            float rs = aw[j];
            float nw = (rs > 0.0f) ? (1.0f / rs) : rs;
            float d0 = ax[j] * nw - verts[3 * r + 0];
            float d1 = ay[j] * nw - verts[3 * r + 1];
            float d2 = az[j] * nw - verts[3 * r + 2];
            float loss = sqrtf(d0 * d0 + d1 * d1 + d2 * d2);
            float w = (r < bd0) ? inv0 : (r < bd1) ? inv1 : (r < bd2) ? inv2
                                                                      : inv3;
            acc += (double)(loss * w * coefs[r]);
        }
    }

    __shared__ double sred[512];
    sred[threadIdx.x] = acc;
    __syncthreads();
    for (int s = blockDim.x / 2; s > 0; s >>= 1) {
        if (threadIdx.x < s) sred[threadIdx.x] += sred[threadIdx.x + s];
        __syncthreads();
    }
    if (threadIdx.x == 0) atomicAdd(partial, sred[0]);
}

__global__ void write_out_kernel(const double* __restrict__ partial,
                                 float* __restrict__ out) {
    if (threadIdx.x == 0 && blockIdx.x == 0)
        out[0] = (float)(partial[0] * 0.25);  // / N_MESHES
}

// ---- Fallback path (R1): global-atomic scatter, needs only 64 + 16V ws ----

__global__ void fb_mesh_counts_kernel(const int* __restrict__ mesh_idx, int v,
                                      int* __restrict__ nvpm) {
    int m = threadIdx.x;
    if (m >= 4) return;
    auto lb = [&](int t) {
        int lo = 0, hi = v;
        while (lo < hi) {
            int mid = (lo + hi) >> 1;
            if (mesh_idx[mid] < t) lo = mid + 1; else hi = mid;
        }
        return lo;
    };
    nvpm[m] = lb(m + 1) - lb(m);
}

__global__ void fb_scatter_kernel(const float* __restrict__ verts,
                                  const float* __restrict__ vals,
                                  const int* __restrict__ rows,
                                  const int* __restrict__ cols,
                                  float* __restrict__ acc, int nnz) {
    int i = blockIdx.x * blockDim.x + threadIdx.x;
    if (i >= nnz) return;
    int r = rows[i];
    int c = cols[i];
    float v = vals[i];
    float* p = acc + 4ll * r;
    atomicAdd(p + 0, v * verts[3 * c + 0]);
    atomicAdd(p + 1, v * verts[3 * c + 1]);
    atomicAdd(p + 2, v * verts[3 * c + 2]);
    atomicAdd(p + 3, v);
}

__global__ void fb_finalize_kernel(const float* __restrict__ verts,
                                   const float* __restrict__ coefs,
                                   const int* __restrict__ mesh_idx,
                                   const float4* __restrict__ acc,
                                   const int* __restrict__ nvpm,
                                   double* __restrict__ partial, int v) {
    float inv0 = 1.0f / (float)nvpm[0];
    float inv1 = 1.0f / (float)nvpm[1];
    float inv2 = 1.0f / (float)nvpm[2];
    float inv3 = 1.0f / (float)nvpm[3];
    double acc_sum = 0.0;
    for (int i = blockIdx.x * blockDim.x + threadIdx.x; i < v;
         i += gridDim.x * blockDim.x) {
        float4 a = acc[i];
        float rs = a.w;
        float nw = (rs > 0.0f) ? (1.0f / rs) : rs;
        float r0 = a.x * nw - verts[3 * i + 0];
        float r1 = a.y * nw - verts[3 * i + 1];
        float r2 = a.z * nw - verts[3 * i + 2];
        float loss = sqrtf(r0 * r0 + r1 * r1 + r2 * r2);
        int m = mesh_idx[i];
        float w = (m == 0) ? inv0 : (m == 1) ? inv1 : (m == 2) ? inv2 : inv3;
        acc_sum += (double)(loss * w * coefs[i]);
    }
    __shared__ double sred[256];
    sred[threadIdx.x] = acc_sum;
    __syncthreads();
    for (int s = blockDim.x / 2; s > 0; s >>= 1) {
        if (threadIdx.x < s) sred[threadIdx.x] += sred[threadIdx.x + s];
        __syncthreads();
    }
    if (threadIdx.x == 0) atomicAdd(partial, sred[0]);
}

extern "C" void kernel_launch(void* const* d_in, const int* in_sizes, int n_in,
                              void* d_out, int out_size, void* d_ws, size_t ws_size,
                              hipStream_t stream) {
    const float* verts    = (const float*)d_in[0];
    const float* lap_vals = (const float*)d_in[1];
    const int*   lap_rows = (const int*)d_in[2];
    const int*   lap_cols = (const int*)d_in[3];
    const int*   mesh_idx = (const int*)d_in[4];
    const float* coefs    = (const float*)d_in[5];
    float* out = (float*)d_out;

    const int V   = in_sizes[0] / 3;
    const int NNZ = in_sizes[1];
    const int B   = (V + BROWS - 1) / BROWS;   // 977 for V = 2M
    int cpb = (NNZ + NB - 1) / NB;
    cpb = (cpb + 3) & ~3;

    char* ws = (char*)d_ws;
    const size_t off_hist    = 262144;
    const size_t off_entries = off_hist + (size_t)BMAX * NB * 2;        // +1MB
    double*         partial  = (double*)(ws + 0);
    int*            nvpm     = (int*)(ws + 8);
    int*            bnd      = (int*)(ws + 24);
    unsigned*       base     = (unsigned*)(ws + 64);
    unsigned*       total    = (unsigned*)(ws + 16384);
    unsigned short* hist     = (unsigned short*)(ws + off_hist);
    uint2*          entries  = (uint2*)(ws + off_entries);

    size_t sort_need = off_entries + (size_t)NNZ * 8 + 64;       // ~113 MB

    (void)hipMemsetAsync(d_ws, 0, 64, stream);

    bool ok_pack = (V <= (1 << 21)) && (B <= BMAX);
    if (ws_size >= sort_need && ok_pack) {
        hist_kernel<<<NB, 512, 0, stream>>>(lap_rows, NNZ, cpb, B, hist);
        scan_blocks_kernel<<<B, 64, 0, stream>>>(hist, total);
        scan_buckets_kernel<<<1, 1024, 0, stream>>>(total, base, B,
                                                    mesh_idx, V, nvpm, bnd);
        scatter_kernel<<<NB, 512, 0, stream>>>(
            lap_rows, lap_cols, lap_vals, hist, base, entries, NNZ, cpb, B);
        bucket_kernel<<<B, 512, 0, stream>>>(entries, base, verts, coefs,
                                             bnd, nvpm, partial, V);
    } else {
        float* acc = (float*)(ws + 64);
        (void)hipMemsetAsync(ws + 64, 0, (size_t)16 * V, stream);
        fb_mesh_counts_kernel<<<1, 64, 0, stream>>>(mesh_idx, V, nvpm);
        fb_scatter_kernel<<<(NNZ + 255) / 256, 256, 0, stream>>>(
            verts, lap_vals, lap_rows, lap_cols, acc, NNZ);
        fb_finalize_kernel<<<2048, 256, 0, stream>>>(
            verts, coefs, mesh_idx, (const float4*)acc, nvpm, partial, V);
    }

    write_out_kernel<<<1, 64, 0, stream>>>(partial, out);
}